// Round 1
// baseline (1336.299 us; speedup 1.0000x reference)
//
#include <hip/hip_runtime.h>

// WeightedConv: messages = einsum('ei,eij->ej', feature[src], weight)
//               out = (feature + segment_sum(messages, dst)) / 2
// N_NODES=32768, N_HIDDEN=32, N_EDGES=262144
// Memory-bound: weight tensor is 1.074 GB read-once; roofline ~170 us @ 6.3 TB/s.

#define N_NODES  32768
#define N_HIDDEN 32
#define N_EDGES  262144

// Kernel 1: out = 0.5 * feature  (initializes the poisoned d_out)
__global__ void wc_init_out(const float* __restrict__ feature,
                            float* __restrict__ out) {
    int idx = blockIdx.x * blockDim.x + threadIdx.x;  // float4 index
    float4 f = ((const float4*)feature)[idx];
    float4 o;
    o.x = 0.5f * f.x;
    o.y = 0.5f * f.y;
    o.z = 0.5f * f.z;
    o.w = 0.5f * f.w;
    ((float4*)out)[idx] = o;
}

// Kernel 2: per-edge matvec + atomic scatter of 0.5*message.
// 8 threads per edge; thread `sub` owns output columns [4*sub, 4*sub+4).
// Per row i, the 8 lanes of an edge read a contiguous 128B segment of
// W[e][i][:] as float4 -> fully coalesced.
__global__ __launch_bounds__(256) void wc_edge(const float* __restrict__ feature,
                                               const float* __restrict__ weight,
                                               const int* __restrict__ src,
                                               const int* __restrict__ dst,
                                               float* __restrict__ out) {
    int tid = blockIdx.x * blockDim.x + threadIdx.x;
    int e   = tid >> 3;   // edge index
    int sub = tid & 7;    // which float4 column group

    int s = src[e];
    int d = dst[e];

    // Load the 32-float source feature row into registers (8 x float4).
    const float4* F = (const float4*)(feature + (size_t)s * N_HIDDEN);
    float4 f[8];
#pragma unroll
    for (int k = 0; k < 8; ++k) f[k] = F[k];

    // Weight row pointer for this thread's column group.
    const float4* W = (const float4*)(weight + (size_t)e * (N_HIDDEN * N_HIDDEN)) + sub;

    float4 acc = make_float4(0.f, 0.f, 0.f, 0.f);
#pragma unroll
    for (int i = 0; i < N_HIDDEN; ++i) {
        float4 w  = W[(size_t)i * (N_HIDDEN / 4)];
        float  fi = ((const float*)f)[i];  // constant index after unroll
        acc.x += fi * w.x;
        acc.y += fi * w.y;
        acc.z += fi * w.z;
        acc.w += fi * w.w;
    }

    float* o = out + (size_t)d * N_HIDDEN + sub * 4;
    atomicAdd(o + 0, 0.5f * acc.x);
    atomicAdd(o + 1, 0.5f * acc.y);
    atomicAdd(o + 2, 0.5f * acc.z);
    atomicAdd(o + 3, 0.5f * acc.w);
}

extern "C" void kernel_launch(void* const* d_in, const int* in_sizes, int n_in,
                              void* d_out, int out_size, void* d_ws, size_t ws_size,
                              hipStream_t stream) {
    const float* feature = (const float*)d_in[0];
    const float* weight  = (const float*)d_in[1];
    const int*   src     = (const int*)d_in[2];
    const int*   dst     = (const int*)d_in[3];
    float*       out     = (float*)d_out;

    // out = feature/2
    {
        int n4 = (N_NODES * N_HIDDEN) / 4;        // 262144 float4s
        wc_init_out<<<n4 / 256, 256, 0, stream>>>(feature, out);
    }
    // out += messages/2 (atomic scatter)
    {
        int threads = N_EDGES * 8;                // 8 threads per edge
        wc_edge<<<threads / 256, 256, 0, stream>>>(feature, weight, src, dst, out);
    }
}